// Round 8
// baseline (59.692 us; speedup 1.0000x reference)
//
#include <hip/hip_runtime.h>

#define SIREN_K 4
#define SIREN_H 32
#define SIREN_C 512
#define SIREN_C4 128   // C / 4
#define OMEGA0 30.0f

typedef float f32x4 __attribute__((ext_vector_type(4)));

// ---------------------------------------------------------------------------
// Kernel 1: build the [K][C] SIREN filter table. One block, 512 threads.
// All weight rows are prefetched into registers at entry so every global
// load is in flight concurrently (one HBM latency exposure instead of three
// barrier-serialized rounds). LDS carries only the K*H hidden states.
// ---------------------------------------------------------------------------
__global__ void siren_table_kernel(const float* __restrict__ w0, const float* __restrict__ b0,
                                   const float* __restrict__ w1, const float* __restrict__ b1,
                                   const float* __restrict__ w2, const float* __restrict__ b2,
                                   const float* __restrict__ w3, const float* __restrict__ b3,
                                   float* __restrict__ ker /* [K][C] */) {
    __shared__ float h[SIREN_K][SIREN_H];
    const int tid = threadIdx.x;          // 512
    const int j = tid & 31, k = tid >> 5; // valid roles for tid<128

    // ---- prefetch: issue ALL global loads up front ----
    const f32x4* w3v = (const f32x4*)(w3 + tid * SIREN_H);  // row c = tid
    f32x4 w3r[SIREN_H / 4];
    #pragma unroll
    for (int q = 0; q < SIREN_H / 4; ++q) w3r[q] = w3v[q];
    const float b3c = b3[tid];

    f32x4 w1r[SIREN_H / 4], w2r[SIREN_H / 4];
    float w0j = 0.f, b0j = 0.f, b1j = 0.f, b2j = 0.f;
    if (tid < SIREN_K * SIREN_H) {
        const f32x4* w1v = (const f32x4*)(w1 + j * SIREN_H);
        const f32x4* w2v = (const f32x4*)(w2 + j * SIREN_H);
        #pragma unroll
        for (int q = 0; q < SIREN_H / 4; ++q) { w1r[q] = w1v[q]; w2r[q] = w2v[q]; }
        w0j = w0[j]; b0j = b0[j]; b1j = b1[j]; b2j = b2[j];
    }

    // ---- stage 0: h = sin(omega0 * pos * w0 + b0) ----
    float hkj = 0.f;
    if (tid < SIREN_K * SIREN_H) {
        float pos = -1.0f + (2.0f / (float)(SIREN_K - 1)) * (float)k;
        if (k == SIREN_K - 1) pos = 1.0f;  // linspace endpoint exact
        pos *= OMEGA0;
        hkj = sinf(pos * w0j + b0j);
        h[k][j] = hkj;
    }
    __syncthreads();

    // ---- stage 1: h = sin(h @ w1.T + b1) ----
    if (tid < SIREN_K * SIREN_H) {
        float s = b1j;
        #pragma unroll
        for (int q = 0; q < SIREN_H / 4; ++q) {
            s += h[k][4*q+0] * w1r[q].x + h[k][4*q+1] * w1r[q].y
               + h[k][4*q+2] * w1r[q].z + h[k][4*q+3] * w1r[q].w;
        }
        hkj = sinf(s);
    }
    __syncthreads();
    if (tid < SIREN_K * SIREN_H) h[k][j] = hkj;
    __syncthreads();

    // ---- stage 2: h = sin(h @ w2.T + b2) ----
    if (tid < SIREN_K * SIREN_H) {
        float s = b2j;
        #pragma unroll
        for (int q = 0; q < SIREN_H / 4; ++q) {
            s += h[k][4*q+0] * w2r[q].x + h[k][4*q+1] * w2r[q].y
               + h[k][4*q+2] * w2r[q].z + h[k][4*q+3] * w2r[q].w;
        }
        hkj = sinf(s);
    }
    __syncthreads();
    if (tid < SIREN_K * SIREN_H) h[k][j] = hkj;
    __syncthreads();

    // ---- stage 3: ker[k][c] = h @ w3.T + b3, c = tid (512 threads) ----
    #pragma unroll
    for (int kk = 0; kk < SIREN_K; ++kk) {
        float s = b3c;
        #pragma unroll
        for (int q = 0; q < SIREN_H / 4; ++q) {
            s += h[kk][4*q+0] * w3r[q].x + h[kk][4*q+1] * w3r[q].y
               + h[kk][4*q+2] * w3r[q].z + h[kk][4*q+3] * w3r[q].w;
        }
        ker[kk * SIREN_C + tid] = s;
    }
}

// ---------------------------------------------------------------------------
// Kernel 2: depthwise strided conv — exact grid, zero loop, 2 outputs/thread.
// out4[idx] = sum_k x4[(idx>>7)*512 + k*128 + (idx&127)] * ker4[k*128 + (idx&127)]
// 8192 blocks x 256 threads; thread handles idx0 = bid*512+tid and idx0+256.
// 8 independent NT x-loads in flight per thread; NT stores on out.
// At the 6.3 TB/s copy ceiling — do not touch.
// ---------------------------------------------------------------------------
__global__ void __launch_bounds__(256) dwconv_kernel(const f32x4* __restrict__ x4,
                                                     const f32x4* __restrict__ ker4,
                                                     f32x4* __restrict__ out4) {
    const int tid = threadIdx.x;
    const int idx0 = blockIdx.x * 512 + tid;
    const int idx1 = idx0 + 256;
    const int c4 = tid & (SIREN_C4 - 1);

    const int bl0 = idx0 >> 7;
    const int bl1 = idx1 >> 7;
    const f32x4* xp0 = x4 + bl0 * (4 * SIREN_C4) + c4;
    const f32x4* xp1 = x4 + bl1 * (4 * SIREN_C4) + c4;

    // 8 independent non-temporal loads — issue all before any use
    const f32x4 a0 = __builtin_nontemporal_load(&xp0[0 * SIREN_C4]);
    const f32x4 b0 = __builtin_nontemporal_load(&xp0[1 * SIREN_C4]);
    const f32x4 c0 = __builtin_nontemporal_load(&xp0[2 * SIREN_C4]);
    const f32x4 d0 = __builtin_nontemporal_load(&xp0[3 * SIREN_C4]);
    const f32x4 a1 = __builtin_nontemporal_load(&xp1[0 * SIREN_C4]);
    const f32x4 b1 = __builtin_nontemporal_load(&xp1[1 * SIREN_C4]);
    const f32x4 c1 = __builtin_nontemporal_load(&xp1[2 * SIREN_C4]);
    const f32x4 d1 = __builtin_nontemporal_load(&xp1[3 * SIREN_C4]);

    // weights: normal loads (tiny, L2-hot, shared by all blocks)
    const f32x4 wv0 = ker4[0 * SIREN_C4 + c4];
    const f32x4 wv1 = ker4[1 * SIREN_C4 + c4];
    const f32x4 wv2 = ker4[2 * SIREN_C4 + c4];
    const f32x4 wv3 = ker4[3 * SIREN_C4 + c4];

    f32x4 o0 = a0 * wv0 + b0 * wv1 + c0 * wv2 + d0 * wv3;
    f32x4 o1 = a1 * wv0 + b1 * wv1 + c1 * wv2 + d1 * wv3;
    __builtin_nontemporal_store(o0, &out4[idx0]);
    __builtin_nontemporal_store(o1, &out4[idx1]);
}

extern "C" void kernel_launch(void* const* d_in, const int* in_sizes, int n_in,
                              void* d_out, int out_size, void* d_ws, size_t ws_size,
                              hipStream_t stream) {
    // Input order (setup_inputs): x, w0, b0, w1, b1, w2, b2, w3, b3, target_len
    const float* x  = (const float*)d_in[0];
    const float* w0 = (const float*)d_in[1];
    const float* b0 = (const float*)d_in[2];
    const float* w1 = (const float*)d_in[3];
    const float* b1 = (const float*)d_in[4];
    const float* w2 = (const float*)d_in[5];
    const float* b2 = (const float*)d_in[6];
    const float* w3 = (const float*)d_in[7];
    const float* b3 = (const float*)d_in[8];

    float* ker = (float*)d_ws;  // K*C floats = 8 KiB

    siren_table_kernel<<<1, 512, 0, stream>>>(w0, b0, w1, b1, w2, b2, w3, b3, ker);

    const int total4 = out_size / 4;        // 4,194,304 f32x4 outputs
    const int blocks = total4 / 512;        // 8192, exact (no tail)
    dwconv_kernel<<<blocks, 256, 0, stream>>>((const f32x4*)x, (const f32x4*)ker,
                                              (f32x4*)d_out);
}